// Round 1
// baseline (1808.608 us; speedup 1.0000x reference)
//
#include <hip/hip_runtime.h>
#include <math.h>

// FFT conv2d: out = irfft2( einsum("bchw,ochw->bohw", rfft2(x), rfft2(w)) )
// B=16, C=32, O=32, H=W=256. fp32 in/out.
//
// Freq-domain layout: [row][h][wb] with row = b*C+c (or o*C+c / b*O+o),
// wb in [0,129), padded pitch 136 complex (row start 64B-aligned).

#define PITCH 136
#define NBIN 129

__device__ __forceinline__ int brev8(int x) {
  return (int)(__brev((unsigned)x) >> 24);
}

// Twiddle table for all 8 radix-2 stages: entry (m-1+j) = exp(sign*i*pi*j/m)
__device__ __forceinline__ void fill_tw(float* twr, float* twi, float sign,
                                        int tid, int nthr) {
  for (int t = tid; t < 255; t += nthr) {
    int level = 31 - __clz(t + 1);
    int m = 1 << level;
    int j = t + 1 - m;
    float ang = sign * 3.14159265358979323846f * (float)j / (float)m;
    float s, c;
    sincosf(ang, &s, &c);
    twr[t] = c;
    twi[t] = s;
  }
}

// ---------------- forward real FFT along W, one row per 64-thread block ----
__global__ __launch_bounds__(64) void rfft_rows(const float* __restrict__ in,
                                                float2* __restrict__ out) {
  __shared__ float sr[256], si[256];
  __shared__ float twr[255], twi[255];
  const int tid = threadIdx.x;
  const long row = blockIdx.x;
  fill_tw(twr, twi, -1.f, tid, 64);
  const float* rp = in + row * 256;
  for (int r = 0; r < 4; ++r) {
    int pos = tid + r * 64;
    int dst = brev8(pos);
    sr[dst] = rp[pos];
    si[dst] = 0.f;
  }
  __syncthreads();
  for (int s = 0; s < 8; ++s) {
    int m = 1 << s;
    for (int k = tid; k < 128; k += 64) {
      int j = k & (m - 1);
      int i0 = ((k >> s) << (s + 1)) + j;
      int i1 = i0 + m;
      float c = twr[m - 1 + j], sn = twi[m - 1 + j];
      float br = sr[i1], bi = si[i1];
      float tr = br * c - bi * sn;
      float ti = br * sn + bi * c;
      float ar = sr[i0], ai = si[i0];
      sr[i0] = ar + tr; si[i0] = ai + ti;
      sr[i1] = ar - tr; si[i1] = ai - ti;
    }
    __syncthreads();
  }
  float2* op = out + row * PITCH;
  for (int k = tid; k < NBIN; k += 64) op[k] = make_float2(sr[k], si[k]);
}

// ---------------- complex FFT along H, in place; tile 256h x 16wb ----------
template <int SIGN>
__global__ __launch_bounds__(256) void fft_cols(float2* __restrict__ data) {
  __shared__ float sr[256 * 16], si[256 * 16];
  __shared__ float twr[255], twi[255];
  const int tid = threadIdx.x;
  const long bc = blockIdx.x;
  const int wb0 = blockIdx.y * 16;
  fill_tw(twr, twi, (float)SIGN, tid, 256);
  float2* base = data + bc * 256 * PITCH;
  for (int r = 0; r < 16; ++r) {
    int e = r * 256 + tid;
    int h = e >> 4, col = e & 15;
    int wb = wb0 + col;
    float2 v = make_float2(0.f, 0.f);
    if (wb < NBIN) v = base[h * PITCH + wb];
    int dst = brev8(h) * 16 + col;
    sr[dst] = v.x;
    si[dst] = v.y;
  }
  __syncthreads();
  for (int s = 0; s < 8; ++s) {
    int m = 1 << s;
    for (int kk = tid; kk < 128 * 16; kk += 256) {
      int col = kk & 15, k = kk >> 4;
      int j = k & (m - 1);
      int i0 = ((k >> s) << (s + 1)) + j;
      int i1 = i0 + m;
      int a0 = i0 * 16 + col, a1 = i1 * 16 + col;
      float c = twr[m - 1 + j], sn = twi[m - 1 + j];
      float br = sr[a1], bi = si[a1];
      float tr = br * c - bi * sn;
      float ti = br * sn + bi * c;
      float ar = sr[a0], ai = si[a0];
      sr[a0] = ar + tr; si[a0] = ai + ti;
      sr[a1] = ar - tr; si[a1] = ai - ti;
    }
    __syncthreads();
  }
  for (int r = 0; r < 16; ++r) {
    int e = r * 256 + tid;
    int h = e >> 4, col = e & 15;
    int wb = wb0 + col;
    if (wb < NBIN)
      base[h * PITCH + wb] = make_float2(sr[h * 16 + col], si[h * 16 + col]);
  }
}

// ---------------- per-bin complex contraction over C, in place into xf -----
// Block: (h, 8-wb tile). Out[b,o] = sum_c X[b,c] * W[o,c], per bin.
__global__ __launch_bounds__(256) void einsum_kernel(float2* __restrict__ xf,
                                                     const float2* __restrict__ wf) {
  __shared__ float2 Xs[16 * 8 * 8];  // [b][c][wb]
  __shared__ float2 Ws[32 * 8 * 8];  // [o][c][wb]
  const int h = blockIdx.x;
  const int wb0 = blockIdx.y * 8;
  const int tid = threadIdx.x;
  const int wb = tid & 7;
  const int b = (tid >> 3) & 15;
  const int og = tid >> 7;  // 0..1, selects o-half
  float2 acc[16];
#pragma unroll
  for (int j = 0; j < 16; ++j) acc[j] = make_float2(0.f, 0.f);

  for (int c0 = 0; c0 < 32; c0 += 8) {
    // load X chunk: [16b][8c][8wb]
#pragma unroll
    for (int r = 0; r < 4; ++r) {
      int e = r * 256 + tid;
      int lwb = e & 7, lc = (e >> 3) & 7, lb = e >> 6;
      int gwb = wb0 + lwb;
      float2 v = make_float2(0.f, 0.f);
      if (gwb < NBIN)
        v = xf[((size_t)(lb * 32 + c0 + lc) * 256 + h) * PITCH + gwb];
      Xs[e] = v;
    }
    // load W chunk: [32o][8c][8wb]
#pragma unroll
    for (int r = 0; r < 8; ++r) {
      int e = r * 256 + tid;
      int lwb = e & 7, lc = (e >> 3) & 7, lo = e >> 6;
      int gwb = wb0 + lwb;
      float2 v = make_float2(0.f, 0.f);
      if (gwb < NBIN)
        v = wf[((size_t)(lo * 32 + c0 + lc) * 256 + h) * PITCH + gwb];
      Ws[e] = v;
    }
    __syncthreads();
#pragma unroll
    for (int c = 0; c < 8; ++c) {
      float2 x = Xs[(b * 8 + c) * 8 + wb];
#pragma unroll
      for (int j = 0; j < 16; ++j) {
        float2 w = Ws[((og * 16 + j) * 8 + c) * 8 + wb];
        acc[j].x += x.x * w.x - x.y * w.y;
        acc[j].y += x.x * w.y + x.y * w.x;
      }
    }
    __syncthreads();
  }
  int gwb = wb0 + wb;
  if (gwb < NBIN) {
#pragma unroll
    for (int j = 0; j < 16; ++j) {
      int o = og * 16 + j;
      xf[((size_t)(b * 32 + o) * 256 + h) * PITCH + gwb] = acc[j];
    }
  }
}

// ---------------- inverse real FFT along W (Hermitian), one row per block --
__global__ __launch_bounds__(64) void irfft_rows(const float2* __restrict__ in,
                                                 float* __restrict__ out) {
  __shared__ float sr[256], si[256];
  __shared__ float twr[255], twi[255];
  const int tid = threadIdx.x;
  const long row = blockIdx.x;
  fill_tw(twr, twi, 1.f, tid, 64);
  const float2* ip = in + row * PITCH;
  for (int k = tid; k < 256; k += 64) {
    float2 v;
    if (k <= 128) {
      v = ip[k];
    } else {
      float2 t = ip[256 - k];
      v = make_float2(t.x, -t.y);
    }
    int dst = brev8(k);
    sr[dst] = v.x;
    si[dst] = v.y;
  }
  __syncthreads();
  for (int s = 0; s < 8; ++s) {
    int m = 1 << s;
    for (int k = tid; k < 128; k += 64) {
      int j = k & (m - 1);
      int i0 = ((k >> s) << (s + 1)) + j;
      int i1 = i0 + m;
      float c = twr[m - 1 + j], sn = twi[m - 1 + j];
      float br = sr[i1], bi = si[i1];
      float tr = br * c - bi * sn;
      float ti = br * sn + bi * c;
      float ar = sr[i0], ai = si[i0];
      sr[i0] = ar + tr; si[i0] = ai + ti;
      sr[i1] = ar - tr; si[i1] = ai - ti;
    }
    __syncthreads();
  }
  const float scale = 1.f / 65536.f;  // 1/(H*W): both inverse FFTs unnormalized
  float* op = out + row * 256;
  for (int p = tid; p < 256; p += 64) op[p] = sr[p] * scale;
}

extern "C" void kernel_launch(void* const* d_in, const int* in_sizes, int n_in,
                              void* d_out, int out_size, void* d_ws, size_t ws_size,
                              hipStream_t stream) {
  const float* x = (const float*)d_in[0];   // (16,32,256,256)
  const float* w = (const float*)d_in[1];   // (32,32,256,256)
  float* out = (float*)d_out;               // (16,32,256,256)

  const size_t xf_rows = 16 * 32;   // 512
  const size_t wf_rows = 32 * 32;   // 1024
  const size_t row_elems = (size_t)256 * PITCH;  // complex per row-image
  const size_t need = (xf_rows + wf_rows) * row_elems * sizeof(float2);
  if (ws_size < need) return;  // workspace too small; bail (bench will flag)

  float2* Xf = (float2*)d_ws;
  float2* Wf = Xf + xf_rows * row_elems;

  // 1) forward row rffts
  rfft_rows<<<dim3(16 * 32 * 256), 64, 0, stream>>>(x, Xf);
  rfft_rows<<<dim3(32 * 32 * 256), 64, 0, stream>>>(w, Wf);
  // 2) forward column ffts (9 tiles of 16 wb cover 129 bins)
  fft_cols<-1><<<dim3(512, 9), 256, 0, stream>>>(Xf);
  fft_cols<-1><<<dim3(1024, 9), 256, 0, stream>>>(Wf);
  // 3) per-bin contraction over C, writes (b,o) rows in place of (b,c)
  einsum_kernel<<<dim3(256, 17), 256, 0, stream>>>(Xf, Wf);
  // 4) inverse column ffts on Out_f
  fft_cols<1><<<dim3(512, 9), 256, 0, stream>>>(Xf);
  // 5) inverse row rffts -> real output, scaled by 1/(H*W)
  irfft_rows<<<dim3(16 * 32 * 256), 64, 0, stream>>>(Xf, out);
}

// Round 2
// 1312.087 us; speedup vs baseline: 1.3784x; 1.3784x over previous
//
#include <hip/hip_runtime.h>
#include <math.h>

// FFT conv2d: out = irfft2( einsum("bchw,ochw->bohw", rfft2(x), rfft2(w)) )
// B=16, C=32, O=32, H=W=256. fp32.
// Freq layout: flat[(row*256 + h)*PITCH + wb], row = b*32+c (or o*32+c / b*32+o),
// wb in [0,129); PITCH=136 complex keeps every (row,h) line 64B-aligned.

#define PITCH 136
#define NBIN 129

__device__ __forceinline__ int brev8(int x) {
  return (int)(__brev((unsigned)x) >> 24);
}

// tw[m-1+j] = exp(sign*i*pi*j/m), all 8 radix-2 stages (255 entries)
__device__ __forceinline__ void fill_tw(float2* tw, float sign, int tid, int nthr) {
  for (int t = tid; t < 255; t += nthr) {
    int level = 31 - __clz(t + 1);
    int m = 1 << level;
    int j = t + 1 - m;
    float invm = __int_as_float((127 - level) << 23);  // 2^-level
    float ang = sign * 3.14159265358979323846f * (float)j * invm;
    float s, c;
    __sincosf(ang, &s, &c);
    tw[t] = make_float2(c, s);
  }
}

// ---------------- forward real FFT along W: 4 rows per 256-thread block ----
__global__ __launch_bounds__(256) void rfft_rows(const float* __restrict__ in,
                                                 float2* __restrict__ out) {
  __shared__ float2 sc[4 * 256];
  __shared__ float2 tw[255];
  const int tid = threadIdx.x;
  fill_tw(tw, -1.f, tid, 256);
  const long row0 = (long)blockIdx.x * 4;
  const int r = tid >> 6, lt = tid & 63;
  // coalesced float4 load of 4 consecutive rows (4 KB)
  float4 v = ((const float4*)(in + row0 * 256))[tid];
  float2* s = sc + r * 256;
  {
    int p = lt * 4;
    s[brev8(p)]     = make_float2(v.x, 0.f);
    s[brev8(p + 1)] = make_float2(v.y, 0.f);
    s[brev8(p + 2)] = make_float2(v.z, 0.f);
    s[brev8(p + 3)] = make_float2(v.w, 0.f);
  }
  __syncthreads();
  for (int st = 0; st < 8; ++st) {
    int m = 1 << st;
#pragma unroll
    for (int half = 0; half < 2; ++half) {
      int k = lt + 64 * half;
      int j = k & (m - 1);
      int i0 = ((k >> st) << (st + 1)) + j;
      int i1 = i0 + m;
      float2 t = tw[m - 1 + j];
      float2 bv = s[i1];
      float tr = bv.x * t.x - bv.y * t.y;
      float ti = bv.x * t.y + bv.y * t.x;
      float2 av = s[i0];
      s[i0] = make_float2(av.x + tr, av.y + ti);
      s[i1] = make_float2(av.x - tr, av.y - ti);
    }
    __syncthreads();
  }
  float2* op = out + (row0 + r) * PITCH;
  float2 b0 = s[2 * lt], b1 = s[2 * lt + 1];
  ((float4*)op)[lt] = make_float4(b0.x, b0.y, b1.x, b1.y);
  if (lt == 0) op[128] = s[128];
}

// ---------------- complex FFT along H, in place; tile 256h x TW_ wb --------
template <int SIGN, int TW_>
__global__ __launch_bounds__(256) void fft_cols(float2* __restrict__ data, int wbbase) {
  constexpr int LGT = (TW_ == 16) ? 4 : 3;
  __shared__ float2 sc[256 * TW_];
  __shared__ float2 tw[255];
  const int tid = threadIdx.x;
  fill_tw(tw, (float)SIGN, tid, 256);
  float2* base = data + (long)blockIdx.x * 256 * PITCH + wbbase + blockIdx.y * TW_;
#pragma unroll
  for (int r = 0; r < TW_ / 2; ++r) {
    int f = r * 256 + tid;                 // float4 index
    int c2 = f & (TW_ / 2 - 1);
    int h = f >> (LGT - 1);
    float4 v = *(const float4*)(base + (long)h * PITCH + c2 * 2);
    int hb = brev8(h);
    sc[hb * TW_ + c2 * 2]     = make_float2(v.x, v.y);
    sc[hb * TW_ + c2 * 2 + 1] = make_float2(v.z, v.w);
  }
  __syncthreads();
  for (int st = 0; st < 8; ++st) {
    int m = 1 << st;
#pragma unroll
    for (int q = 0; q < TW_ / 2; ++q) {
      int kk = q * 256 + tid;
      int col = kk & (TW_ - 1);
      int k = kk >> LGT;
      int j = k & (m - 1);
      int i0 = ((k >> st) << (st + 1)) + j;
      int i1 = i0 + m;
      float2 t = tw[m - 1 + j];
      float2 bv = sc[i1 * TW_ + col];
      float tr = bv.x * t.x - bv.y * t.y;
      float ti = bv.x * t.y + bv.y * t.x;
      float2 av = sc[i0 * TW_ + col];
      sc[i0 * TW_ + col] = make_float2(av.x + tr, av.y + ti);
      sc[i1 * TW_ + col] = make_float2(av.x - tr, av.y - ti);
    }
    __syncthreads();
  }
#pragma unroll
  for (int r = 0; r < TW_ / 2; ++r) {
    int f = r * 256 + tid;
    int c2 = f & (TW_ / 2 - 1);
    int h = f >> (LGT - 1);
    float2 a = sc[h * TW_ + c2 * 2], b = sc[h * TW_ + c2 * 2 + 1];
    *(float4*)(base + (long)h * PITCH + c2 * 2) = make_float4(a.x, a.y, b.x, b.y);
  }
}

// ---------------- per-bin contraction over C (bins 0..127, no masking) -----
// Block = (h, 16-wb tile). Thread = (b, wb), computes all 32 o. In-place.
__global__ __launch_bounds__(256, 3) void einsum_kernel(float2* __restrict__ xf,
                                                        const float2* __restrict__ wf) {
  __shared__ float2 Xs[8 * 256];      // [c][b*16+wb]
  __shared__ float2 Ws[8 * 32 * 16];  // [c][o][wb]
  const int h = blockIdx.x;
  const int tid = threadIdx.x;
  const int wb = tid & 15, b = tid >> 4;
  const long hoff = (long)h * PITCH + blockIdx.y * 16;
  float2 acc[32];
#pragma unroll
  for (int o = 0; o < 32; ++o) acc[o] = make_float2(0.f, 0.f);

  for (int c0 = 0; c0 < 32; c0 += 8) {
#pragma unroll
    for (int r = 0; r < 4; ++r) {          // X: 16b x 8c rows, 8 float4 each
      int e = r * 256 + tid;
      int lw = e & 7, lc = (e >> 3) & 7, lb = e >> 6;
      float4 v = *(const float4*)(xf + (long)(lb * 32 + c0 + lc) * 256 * PITCH + hoff + lw * 2);
      Xs[lc * 256 + lb * 16 + lw * 2]     = make_float2(v.x, v.y);
      Xs[lc * 256 + lb * 16 + lw * 2 + 1] = make_float2(v.z, v.w);
    }
#pragma unroll
    for (int r = 0; r < 8; ++r) {          // W: 32o x 8c rows
      int e = r * 256 + tid;
      int lw = e & 7, lc = (e >> 3) & 7, lo = e >> 6;
      float4 v = *(const float4*)(wf + (long)(lo * 32 + c0 + lc) * 256 * PITCH + hoff + lw * 2);
      Ws[(lc * 32 + lo) * 16 + lw * 2]     = make_float2(v.x, v.y);
      Ws[(lc * 32 + lo) * 16 + lw * 2 + 1] = make_float2(v.z, v.w);
    }
    __syncthreads();
#pragma unroll
    for (int c = 0; c < 8; ++c) {
      float2 xv = Xs[c * 256 + tid];       // lane-consecutive: conflict-free
#pragma unroll
      for (int o = 0; o < 32; ++o) {
        float2 wv = Ws[(c * 32 + o) * 16 + wb];  // 128B broadcast: conflict-free
        acc[o].x = fmaf(xv.x, wv.x, fmaf(-xv.y, wv.y, acc[o].x));
        acc[o].y = fmaf(xv.x, wv.y, fmaf(xv.y, wv.x, acc[o].y));
      }
    }
    __syncthreads();
  }
#pragma unroll
  for (int o = 0; o < 32; ++o)
    xf[(long)(b * 32 + o) * 256 * PITCH + hoff + wb] = acc[o];
}

// ---------------- Nyquist column (wb = 128) contraction --------------------
__global__ __launch_bounds__(256) void einsum_nyq(float2* __restrict__ xf,
                                                  const float2* __restrict__ wf) {
  __shared__ float2 Xs[512];   // [b*32+c]
  __shared__ float2 Ws[1024];  // [o*32+c]
  const int h = blockIdx.x, tid = threadIdx.x;
  const long off = (long)h * PITCH + 128;
  for (int e = tid; e < 512; e += 256)  Xs[e] = xf[(long)e * 256 * PITCH + off];
  for (int e = tid; e < 1024; e += 256) Ws[e] = wf[(long)e * 256 * PITCH + off];
  __syncthreads();
  const int b = tid >> 4, o0 = (tid & 15) * 2;
  float2 a0 = make_float2(0.f, 0.f), a1 = make_float2(0.f, 0.f);
#pragma unroll
  for (int c = 0; c < 32; ++c) {
    float2 x = Xs[b * 32 + c];
    float2 w0 = Ws[o0 * 32 + c];
    float2 w1 = Ws[(o0 + 1) * 32 + c];
    a0.x = fmaf(x.x, w0.x, fmaf(-x.y, w0.y, a0.x));
    a0.y = fmaf(x.x, w0.y, fmaf(x.y, w0.x, a0.y));
    a1.x = fmaf(x.x, w1.x, fmaf(-x.y, w1.y, a1.x));
    a1.y = fmaf(x.x, w1.y, fmaf(x.y, w1.x, a1.y));
  }
  xf[(long)(b * 32 + o0) * 256 * PITCH + off] = a0;
  xf[(long)(b * 32 + o0 + 1) * 256 * PITCH + off] = a1;
}

// ---------------- inverse real FFT along W: 4 rows per 256-thread block ----
__global__ __launch_bounds__(256) void irfft_rows(const float2* __restrict__ in,
                                                  float* __restrict__ out) {
  __shared__ float2 sc[4 * 256];
  __shared__ float2 tw[255];
  const int tid = threadIdx.x;
  fill_tw(tw, 1.f, tid, 256);
  const long row0 = (long)blockIdx.x * 4;
  const int r = tid >> 6, lt = tid & 63;
  const float2* ip = in + (row0 + r) * PITCH;
  float2* s = sc + r * 256;
#pragma unroll
  for (int i = 0; i < 4; ++i) {
    int k = lt + 64 * i;
    float2 v;
    if (k <= 128) v = ip[k];
    else { float2 t2 = ip[256 - k]; v = make_float2(t2.x, -t2.y); }
    s[brev8(k)] = v;
  }
  __syncthreads();
  for (int st = 0; st < 8; ++st) {
    int m = 1 << st;
#pragma unroll
    for (int half = 0; half < 2; ++half) {
      int k = lt + 64 * half;
      int j = k & (m - 1);
      int i0 = ((k >> st) << (st + 1)) + j;
      int i1 = i0 + m;
      float2 t = tw[m - 1 + j];
      float2 bv = s[i1];
      float tr = bv.x * t.x - bv.y * t.y;
      float ti = bv.x * t.y + bv.y * t.x;
      float2 av = s[i0];
      s[i0] = make_float2(av.x + tr, av.y + ti);
      s[i1] = make_float2(av.x - tr, av.y - ti);
    }
    __syncthreads();
  }
  const float scale = 1.f / 65536.f;  // 1/(H*W)
  int p = lt * 4;
  float4 ov = make_float4(s[p].x * scale, s[p + 1].x * scale,
                          s[p + 2].x * scale, s[p + 3].x * scale);
  ((float4*)(out + (row0 + r) * 256))[lt] = ov;
}

extern "C" void kernel_launch(void* const* d_in, const int* in_sizes, int n_in,
                              void* d_out, int out_size, void* d_ws, size_t ws_size,
                              hipStream_t stream) {
  const float* x = (const float*)d_in[0];   // (16,32,256,256)
  const float* w = (const float*)d_in[1];   // (32,32,256,256)
  float* out = (float*)d_out;               // (16,32,256,256)

  const size_t row_elems = (size_t)256 * PITCH;
  const size_t need = (size_t)(512 + 1024) * row_elems * sizeof(float2);
  if (ws_size < need) return;

  float2* Xf = (float2*)d_ws;
  float2* Wf = Xf + (size_t)512 * row_elems;

  // 1) forward row rffts (4 rows / block)
  rfft_rows<<<dim3(16 * 32 * 256 / 4), 256, 0, stream>>>(x, Xf);
  rfft_rows<<<dim3(32 * 32 * 256 / 4), 256, 0, stream>>>(w, Wf);
  // 2) forward column ffts: 8 full 16-wide tiles + one 8-wide tail (bins 128..135,
  //    cols 129..135 are in-pitch pad garbage, FFT'd harmlessly column-independent)
  fft_cols<-1, 16><<<dim3(512, 8), 256, 0, stream>>>(Xf, 0);
  fft_cols<-1, 8><<<dim3(512, 1), 256, 0, stream>>>(Xf, 128);
  fft_cols<-1, 16><<<dim3(1024, 8), 256, 0, stream>>>(Wf, 0);
  fft_cols<-1, 8><<<dim3(1024, 1), 256, 0, stream>>>(Wf, 128);
  // 3) contraction (in place: Out rows b*32+o overwrite X rows b*32+c)
  einsum_kernel<<<dim3(256, 8), 256, 0, stream>>>(Xf, Wf);
  einsum_nyq<<<dim3(256), 256, 0, stream>>>(Xf, Wf);
  // 4) inverse column ffts on Out_f
  fft_cols<1, 16><<<dim3(512, 8), 256, 0, stream>>>(Xf, 0);
  fft_cols<1, 8><<<dim3(512, 1), 256, 0, stream>>>(Xf, 128);
  // 5) inverse row rffts -> real output (scaled 1/65536)
  irfft_rows<<<dim3(16 * 32 * 256 / 4), 256, 0, stream>>>(Xf, out);
}